// Round 9
// baseline (102.743 us; speedup 1.0000x reference)
//
#include <hip/hip_runtime.h>
#include <math.h>

#define NB 16
#define SEQ 1024
#define NHEAD 8

typedef __attribute__((ext_vector_type(4))) float f32x4;

// Single fused kernel. Algebra: q,k,v are 3-tap convs of xn, so
//   score(t,s) = u(t)^T M u(s),  u(t)=(xn[t-1],xn[t],xn[t+1],1),  M: 4x4/head
//   (w_out o V)(s) = hc . u(s)                                  hc: 4/head
// Attention reduces to, per (h,t): alpha = u(t)^T M (4 scalars), then a
// 1024-step scan p=exp2(3FMA); ss+=p; dd=fma(p,vp,dd). No MFMA, no atomics.
// Block = (b, chunk of 32 t); thread = (h, t). 512 blocks x 256 threads.
__global__ void __launch_bounds__(256) k_fused(
    const float* __restrict__ x, const float* __restrict__ gam,
    const float* __restrict__ be, const float* __restrict__ mu,
    const float* __restrict__ va, const float* __restrict__ w_in,
    const float* __restrict__ b_in, const float* __restrict__ w_out,
    const float* __restrict__ b_out, float* __restrict__ out) {
  __shared__ float xsl[1032];          // xn row + 8 zero pad
  __shared__ float vps[NHEAD][1032];   // vp rows + pads
  __shared__ float Ms[NHEAD][16];
  __shared__ float hcs[NHEAD][4];
  __shared__ float rsum[NHEAD][32];

  int bid = blockIdx.x;
  int b = bid >> 5, chunk = bid & 31;
  int tid = threadIdx.x;

  // ---- BN -> xn (LDS). 4 consecutive t per thread. ----
  int t4 = tid * 4;
  f32x4 xv  = *(const f32x4*)(x + b*SEQ + t4);
  f32x4 muv = *(const f32x4*)(mu + t4);
  f32x4 vav = *(const f32x4*)(va + t4);
  f32x4 gv  = *(const f32x4*)(gam + t4);
  f32x4 bev = *(const f32x4*)(be + t4);
  f32x4 xn4;
  #pragma unroll
  for (int u = 0; u < 4; ++u)
    xn4[u] = (xv[u] - muv[u]) * rsqrtf(vav[u] + 1e-5f) * gv[u] + bev[u];
  *(f32x4*)(xsl + t4) = xn4;
  if (tid < 8) xsl[1024 + tid] = 0.f;

  // ---- per-head M (tid<128) and hc (tid 128..159); weights L2-hot ----
  const float QS2 = 0.125f * 1.4426950408889634f;   // scale^2 * log2(e)
  if (tid < 128) {
    int hh = tid >> 4, ij = tid & 15, i = ij >> 2, j = ij & 3;
    int oq = hh * 192, ok = oq + 64;
    float acc = 0.f;
    #pragma unroll 8
    for (int c = 0; c < 64; ++c) {
      float wq = (i < 3) ? w_in[(oq + c)*3 + i] : b_in[oq + c];
      float wk = (j < 3) ? w_in[(ok + c)*3 + j] : b_in[ok + c];
      acc = fmaf(wq, wk, acc);
    }
    Ms[hh][ij] = acc * QS2;
  } else if (tid < 160) {
    int idx = tid - 128, hh = idx >> 2, jj = idx & 3;
    int ov = hh * 192 + 128;
    float acc = 0.f;
    #pragma unroll 8
    for (int c = 0; c < 64; ++c) {
      float wv = (jj < 3) ? w_in[(ov + c)*3 + jj] : b_in[ov + c];
      acc = fmaf(w_out[hh*64 + c], wv, acc);
    }
    hcs[hh][jj] = acc;
  }
  __syncthreads();

  // ---- vp rows: thread (h, tl) fills s = 32k + tl ----
  int h = tid >> 5, tl = tid & 31;
  {
    float hc0 = hcs[h][0], hc1 = hcs[h][1], hc2 = hcs[h][2], hc3 = hcs[h][3];
    #pragma unroll 4
    for (int k2 = 0; k2 < 32; ++k2) {
      int s = k2*32 + tl;
      float xm = (s > 0) ? xsl[s-1] : 0.f;
      vps[h][s] = fmaf(hc0, xm, fmaf(hc1, xsl[s], fmaf(hc2, xsl[s+1], hc3)));
    }
    if (tl < 8) vps[h][1024 + tl] = 0.f;
  }
  __syncthreads();

  // ---- alpha(t) = u(t)^T M ----
  int t = chunk*32 + tl;
  float um = (t > 0) ? xsl[t-1] : 0.f;
  float u0 = xsl[t], up = xsl[t+1];
  const float* Mh = Ms[h];
  float a0 = fmaf(um, Mh[0], fmaf(u0, Mh[4],  fmaf(up, Mh[8],  Mh[12])));
  float a1 = fmaf(um, Mh[1], fmaf(u0, Mh[5],  fmaf(up, Mh[9],  Mh[13])));
  float a2 = fmaf(um, Mh[2], fmaf(u0, Mh[6],  fmaf(up, Mh[10], Mh[14])));
  float a3 = fmaf(um, Mh[3], fmaf(u0, Mh[7],  fmaf(up, Mh[11], Mh[15])));

  // ---- 1024-step scan over LDS broadcasts ----
  const f32x4* x4 = (const f32x4*)xsl;
  const f32x4* v4 = (const f32x4*)&vps[h][0];
  float ss = 0.f, dd = 0.f;
  f32x4 cA = x4[0], vA = v4[0];
  f32x4 cB = x4[1], vB = v4[1];
  float prevW = 0.f;                       // xn[-1] = 0 (conv zero-pad)

#define STEP(XM, X0, XP, VV) { \
  float sc = fmaf(a0, (XM), fmaf(a1, (X0), fmaf(a2, (XP), a3))); \
  float p = __builtin_amdgcn_exp2f(sc); \
  ss += p; dd = fmaf(p, (VV), dd); }

  #pragma unroll 4
  for (int k = 0; k < 256; ++k) {
    f32x4 cC = x4[k+2];                    // k=254,255 hit zero pads
    f32x4 vC = v4[k+2];
    STEP(prevW, cA.x, cA.y, vA.x)
    STEP(cA.x,  cA.y, cA.z, vA.y)
    STEP(cA.y,  cA.z, cA.w, vA.z)
    STEP(cA.z,  cA.w, cB.x, vA.w)
    prevW = cA.w; cA = cB; cB = cC; vA = vB; vB = vC;
  }
#undef STEP

  rsum[h][tl] = dd / ss;
  __syncthreads();

  // ---- combine 8 heads, add residual + b_out, single plain store ----
  if (tid < 32) {
    int to = chunk*32 + tid;
    float acc = xsl[to] + b_out[0];
    #pragma unroll
    for (int hh = 0; hh < NHEAD; ++hh) acc += rsum[hh][tid];
    out[b*SEQ + to] = acc;
  }
}

extern "C" void kernel_launch(void* const* d_in, const int* in_sizes, int n_in,
                              void* d_out, int out_size, void* d_ws, size_t ws_size,
                              hipStream_t stream) {
  const float* x   = (const float*)d_in[0];
  const float* g   = (const float*)d_in[1];
  const float* be  = (const float*)d_in[2];
  const float* mu  = (const float*)d_in[3];
  const float* va  = (const float*)d_in[4];
  const float* win = (const float*)d_in[5];
  const float* bin = (const float*)d_in[6];
  const float* wo  = (const float*)d_in[7];
  const float* bo  = (const float*)d_in[8];
  float* out = (float*)d_out;
  (void)d_ws; (void)ws_size; (void)in_sizes; (void)n_in; (void)out_size;

  hipLaunchKernelGGL(k_fused, dim3(NB * 32), dim3(256), 0, stream,
                     x, g, be, mu, va, win, bin, wo, bo, out);
}

// Round 16
// 98.907 us; speedup vs baseline: 1.0388x; 1.0388x over previous
//
#include <hip/hip_runtime.h>
#include <math.h>

#define NB 16
#define SEQ 1024
#define NHEAD 8

typedef __attribute__((ext_vector_type(4))) float f32x4;

// Single fused kernel. Algebra: q,k,v are 3-tap convs of xn, so
//   score(t,s) = u(t)^T M u(s),  u(t)=(xn[t-1],xn[t],xn[t+1],1),  M: 4x4/head
//   (w_out o V)(s) = hc . u(s)                                  hc: 4/head
// Per (h,t): alpha = u(t)^T M (4 scalars), then scan p=exp2(3FMA);
// ss+=p; dd=fma(p,vp,dd). No MFMA, no atomics.
// Block = (b, chunk of 32 t), 1024 threads = (s-quarter q, h, tl): each
// thread scans 256 s; 4 partials per (h,t) summed in LDS. 512 blocks ->
// 2 blocks/CU x 16 waves = 32 waves/CU (100% cap), fixing R9's 16% occupancy.
__global__ void __launch_bounds__(1024) k_fused(
    const float* __restrict__ x, const float* __restrict__ gam,
    const float* __restrict__ be, const float* __restrict__ mu,
    const float* __restrict__ va, const float* __restrict__ w_in,
    const float* __restrict__ b_in, const float* __restrict__ w_out,
    const float* __restrict__ b_out, float* __restrict__ out) {
  __shared__ float xsl[1032];          // xn row + 8 zero pad
  __shared__ float vps[NHEAD][1032];   // vp rows + pads
  __shared__ float Ms[NHEAD][16];
  __shared__ float hcs[NHEAD][4];
  __shared__ float ssp[4][NHEAD][32];  // per-quarter partial sums
  __shared__ float ddp[4][NHEAD][32];
  __shared__ float rsum[NHEAD][32];

  int bid = blockIdx.x;
  int b = bid >> 5, chunk = bid & 31;
  int tid = threadIdx.x;

  // ---- BN -> xn (LDS), one t per thread ----
  {
    float xv = x[b*SEQ + tid];
    xsl[tid] = (xv - mu[tid]) * rsqrtf(va[tid] + 1e-5f) * gam[tid] + be[tid];
  }
  if (tid < 8) xsl[1024 + tid] = 0.f;

  // ---- per-head M (tid<128) and hc (tid 128..159); weights L2-hot ----
  const float QS2 = 0.125f * 1.4426950408889634f;   // scale^2 * log2(e)
  if (tid < 128) {
    int hh = tid >> 4, ij = tid & 15, i = ij >> 2, j = ij & 3;
    int oq = hh * 192, ok = oq + 64;
    float acc = 0.f;
    #pragma unroll 8
    for (int c = 0; c < 64; ++c) {
      float wq = (i < 3) ? w_in[(oq + c)*3 + i] : b_in[oq + c];
      float wk = (j < 3) ? w_in[(ok + c)*3 + j] : b_in[ok + c];
      acc = fmaf(wq, wk, acc);
    }
    Ms[hh][ij] = acc * QS2;
  } else if (tid < 160) {
    int idx = tid - 128, hh = idx >> 2, jj = idx & 3;
    int ov = hh * 192 + 128;
    float acc = 0.f;
    #pragma unroll 8
    for (int c = 0; c < 64; ++c) {
      float wv = (jj < 3) ? w_in[(ov + c)*3 + jj] : b_in[ov + c];
      acc = fmaf(w_out[hh*64 + c], wv, acc);
    }
    hcs[hh][jj] = acc;
  }
  __syncthreads();

  // ---- vp rows: thread (hh = tid>>7, sl = tid&127) fills 8 s-positions ----
  {
    int hh = tid >> 7, sl = tid & 127;
    float hc0 = hcs[hh][0], hc1 = hcs[hh][1], hc2 = hcs[hh][2], hc3 = hcs[hh][3];
    #pragma unroll
    for (int k2 = 0; k2 < 8; ++k2) {
      int s = k2*128 + sl;
      float xm = (s > 0) ? xsl[s-1] : 0.f;
      vps[hh][s] = fmaf(hc0, xm, fmaf(hc1, xsl[s], fmaf(hc2, xsl[s+1], hc3)));
    }
    if (sl < 8) vps[hh][1024 + sl] = 0.f;
  }
  __syncthreads();

  // ---- thread = (q, h, tl): alpha(t) = u(t)^T M ----
  int q = tid >> 8, h = (tid >> 5) & 7, tl = tid & 31;
  int t = chunk*32 + tl;
  float um = (t > 0) ? xsl[t-1] : 0.f;
  float u0 = xsl[t], up = xsl[t+1];
  const float* Mh = Ms[h];
  float a0 = fmaf(um, Mh[0], fmaf(u0, Mh[4],  fmaf(up, Mh[8],  Mh[12])));
  float a1 = fmaf(um, Mh[1], fmaf(u0, Mh[5],  fmaf(up, Mh[9],  Mh[13])));
  float a2 = fmaf(um, Mh[2], fmaf(u0, Mh[6],  fmaf(up, Mh[10], Mh[14])));
  float a3 = fmaf(um, Mh[3], fmaf(u0, Mh[7],  fmaf(up, Mh[11], Mh[15])));

  // ---- 256-step scan over s-quarter q (LDS broadcasts) ----
  const f32x4* x4 = (const f32x4*)xsl;
  const f32x4* v4 = (const f32x4*)&vps[h][0];
  int j0 = q * 64;
  float ss = 0.f, dd = 0.f;
  f32x4 cA = x4[j0], vA = v4[j0];
  f32x4 cB = x4[j0+1], vB = v4[j0+1];
  float prevW = (q == 0) ? 0.f : xsl[q*256 - 1];   // xn[-1]=0 (conv zero-pad)

#define STEP(XM, X0, XP, VV) { \
  float sc = fmaf(a0, (XM), fmaf(a1, (X0), fmaf(a2, (XP), a3))); \
  float p = __builtin_amdgcn_exp2f(sc); \
  ss += p; dd = fmaf(p, (VV), dd); }

  #pragma unroll 4
  for (int k = 0; k < 64; ++k) {
    f32x4 cC = x4[j0 + k + 2];           // last iters hit zero pads (<=257)
    f32x4 vC = v4[j0 + k + 2];
    STEP(prevW, cA.x, cA.y, vA.x)
    STEP(cA.x,  cA.y, cA.z, vA.y)
    STEP(cA.y,  cA.z, cA.w, vA.z)
    STEP(cA.z,  cA.w, cB.x, vA.w)
    prevW = cA.w; cA = cB; cB = cC; vA = vB; vB = vC;
  }
#undef STEP

  ssp[q][h][tl] = ss;
  ddp[q][h][tl] = dd;
  __syncthreads();

  // ---- combine 4 quarters (plain sums), then 8 heads + residual ----
  if (tid < 256) {   // q == 0 threads
    float sT = ssp[0][h][tl] + ssp[1][h][tl] + ssp[2][h][tl] + ssp[3][h][tl];
    float dT = ddp[0][h][tl] + ddp[1][h][tl] + ddp[2][h][tl] + ddp[3][h][tl];
    rsum[h][tl] = dT / sT;
  }
  __syncthreads();
  if (tid < 32) {
    int to = chunk*32 + tid;
    float acc = xsl[to] + b_out[0];
    #pragma unroll
    for (int hh = 0; hh < NHEAD; ++hh) acc += rsum[hh][tid];
    out[b*SEQ + to] = acc;
  }
}

extern "C" void kernel_launch(void* const* d_in, const int* in_sizes, int n_in,
                              void* d_out, int out_size, void* d_ws, size_t ws_size,
                              hipStream_t stream) {
  const float* x   = (const float*)d_in[0];
  const float* g   = (const float*)d_in[1];
  const float* be  = (const float*)d_in[2];
  const float* mu  = (const float*)d_in[3];
  const float* va  = (const float*)d_in[4];
  const float* win = (const float*)d_in[5];
  const float* bin = (const float*)d_in[6];
  const float* wo  = (const float*)d_in[7];
  const float* bo  = (const float*)d_in[8];
  float* out = (float*)d_out;
  (void)d_ws; (void)ws_size; (void)in_sizes; (void)n_in; (void)out_size;

  hipLaunchKernelGGL(k_fused, dim3(NB * 32), dim3(1024), 0, stream,
                     x, g, be, mu, va, win, bin, wo, bo, out);
}